// Round 6
// baseline (245.330 us; speedup 1.0000x reference)
//
#include <hip/hip_runtime.h>
#include <math.h>
#include <stdint.h>
#include <vector>

#ifndef M_PI
#define M_PI 3.14159265358979323846
#endif

#define S_    128
#define B_    128
#define E_    64
#define H_    8
#define T_    12
#define FAN_  72
#define NOPS_ 30
#define MAXG_ 30

// ---------------------------------------------------------------------------
// numpy.random.RandomState(1234) legacy stream (validated round 4/5).
// ---------------------------------------------------------------------------
struct MT19937 {
    uint32_t mt[624];
    int idx;
    void seed(uint32_t s) {
        for (int i = 0; i < 624; i++) {
            mt[i] = s;
            s = 1812433253u * (s ^ (s >> 30)) + (uint32_t)i + 1u;
        }
        idx = 624;
    }
    uint32_t next() {
        if (idx >= 624) {
            for (int i = 0; i < 624; i++) {
                uint32_t y = (mt[i] & 0x80000000u) | (mt[(i + 1) % 624] & 0x7fffffffu);
                uint32_t v = mt[(i + 397) % 624] ^ (y >> 1);
                mt[i] = (y & 1u) ? (v ^ 0x9908b0dfu) : v;
            }
            idx = 0;
        }
        uint32_t y = mt[idx++];
        y ^= y >> 11;
        y ^= (y << 7)  & 0x9d2c5680u;
        y ^= (y << 15) & 0xefc60000u;
        y ^= y >> 18;
        return y;
    }
    uint32_t randint(uint32_t n) {
        uint32_t rng = n - 1u, mask = rng;
        mask |= mask >> 1; mask |= mask >> 2; mask |= mask >> 4;
        mask |= mask >> 8; mask |= mask >> 16;
        uint32_t v;
        do { v = next() & mask; } while (v > rng);
        return v;
    }
    double uniform(double lo, double hi) {
        uint32_t a = next() >> 5, b = next() >> 6;
        double d = ((double)a * 67108864.0 + (double)b) / 9007199254740992.0;
        return lo + (hi - lo) * d;
    }
};

// ---------------------------------------------------------------------------
// Host-side circuit optimizer (validated round 5): leading-fold, commuting
// merges, CNOT cancellation, trailing extraction into per-wire end matrices.
// ---------------------------------------------------------------------------
struct C2h { double r, i; };
static inline C2h cmul(C2h a, C2h b) { return { a.r*b.r - a.i*b.i, a.r*b.i + a.i*b.r }; }
static inline C2h cadd(C2h a, C2h b) { return { a.r + b.r, a.i + b.i }; }
struct M22 { C2h m[2][2]; };
static inline M22 mmul(const M22& A, const M22& B) {
    M22 C;
    for (int i = 0; i < 2; i++)
        for (int j = 0; j < 2; j++)
            C.m[i][j] = cadd(cmul(A.m[i][0], B.m[0][j]), cmul(A.m[i][1], B.m[1][j]));
    return C;
}
static inline M22 ident() { return { { { {1,0},{0,0} }, { {0,0},{1,0} } } }; }

struct HostOp { int kind; int a, b; M22 U; };

struct QCircuit {
    int   n;
    int   type[MAXG_];
    int   w1[MAXG_];
    int   w2[MAXG_];
    float U[MAXG_][8];   // [00r,00i,01r,01i,10r,10i,11r,11i]
    float initM[8][8];
    float endM[8][8];
};

static void putM(float* dst, const M22& M) {
    dst[0] = (float)M.m[0][0].r; dst[1] = (float)M.m[0][0].i;
    dst[2] = (float)M.m[0][1].r; dst[3] = (float)M.m[0][1].i;
    dst[4] = (float)M.m[1][0].r; dst[5] = (float)M.m[1][0].i;
    dst[6] = (float)M.m[1][1].r; dst[7] = (float)M.m[1][1].i;
}

static QCircuit build_circuit() {
    MT19937 rng; rng.seed(1234u);
    std::vector<HostOp> raw;
    for (int i = 0; i < NOPS_; i++) {
        uint32_t kind = rng.randint(4);
        if (kind == 3u) {
            int c = (int)rng.randint(8);
            int t = (int)rng.randint(7);
            if (t >= c) t += 1;
            raw.push_back({1, c, t, ident()});
        } else {
            int g = (int)(kind % 3u);
            int w = (int)rng.randint(8);
            double th = rng.uniform(0.0, 2.0 * M_PI);
            double c = cos(0.5 * th), s = sin(0.5 * th);
            M22 M;
            if (g == 0)      M = { { { {c,0},{0,-s} }, { {0,-s},{c,0} } } };   // rx
            else if (g == 1) M = { { { {c,0},{-s,0} }, { {s,0},{c,0} } } };    // ry
            else             M = { { { {c,-s},{0,0} }, { {0,0},{c,s} } } };    // rz
            raw.push_back({0, w, -1, M});
        }
    }

    std::vector<HostOp> items;
    M22 initM[8], endM[8];
    for (int w = 0; w < 8; w++) { initM[w] = ident(); endM[w] = ident(); }

    for (const HostOp& op : raw) {
        if (op.kind == 0) {
            int w = op.a, k = (int)items.size() - 1;
            bool merged = false;
            while (k >= 0) {
                if (items[k].kind == 0) {
                    if (items[k].a == w) { items[k].U = mmul(op.U, items[k].U); merged = true; break; }
                    k--;
                } else {
                    if (w == items[k].a || w == items[k].b) break;
                    k--;
                }
            }
            if (merged) continue;
            if (k < 0) { initM[w] = mmul(op.U, initM[w]); continue; }
            items.push_back(op);
        } else {
            int c = op.a, t = op.b, k = (int)items.size() - 1;
            bool cancelled = false;
            while (k >= 0) {
                if (items[k].kind == 0) {
                    int w = items[k].a;
                    if (w == c || w == t) break;
                    k--;
                } else {
                    int c2 = items[k].a, t2 = items[k].b;
                    if (c2 == c && t2 == t) { items.erase(items.begin() + k); cancelled = true; break; }
                    if (c2 != t && t2 != c) k--;
                    else break;
                }
            }
            if (!cancelled) items.push_back(op);
        }
    }
    bool blocked[8] = {};
    for (int k = (int)items.size() - 1; k >= 0; k--) {
        if (items[k].kind == 0) {
            int w = items[k].a;
            if (!blocked[w]) {
                endM[w] = mmul(endM[w], items[k].U);
                items.erase(items.begin() + k);
            }
        } else {
            blocked[items[k].a] = blocked[items[k].b] = true;
        }
    }

    QCircuit q = {};
    q.n = (int)items.size();
    for (int i = 0; i < q.n; i++) {
        q.type[i] = items[i].kind;
        q.w1[i]   = items[i].a;
        q.w2[i]   = items[i].b;
        putM(q.U[i], items[i].U);
    }
    for (int w = 0; w < 8; w++) { putM(q.initM[w], initM[w]); putM(q.endM[w], endM[w]); }
    return q;
}

// ---------------------------------------------------------------------------
// Device helpers
// ---------------------------------------------------------------------------
__device__ __forceinline__ float sigmoid_f(float x) { return 1.f / (1.f + __expf(-x)); }
__device__ __forceinline__ float tanh_f(float x) {
    float e = __expf(2.f * x);
    return 1.f - 2.f / (e + 1.f);
}

template<int CTRL>
__device__ __forceinline__ float dppf(float x) {
    union { float f; int i; } u, r;
    u.f = x;
    r.i = __builtin_amdgcn_update_dpp(0, u.i, CTRL, 0xF, 0xF, true);
    return r.f;
}

// lane-xor exchange by mask M (DPP for 1/2/4/8, DS for 16/32) — validated r5
template<int M>
__device__ __forceinline__ float lane_xor(float x, int lane) {
    if constexpr (M == 1)  return dppf<0xB1>(x);                 // quad_perm [1,0,3,2]
    else if constexpr (M == 2) return dppf<0x4E>(x);             // quad_perm [2,3,0,1]
    else if constexpr (M == 4) {
        float a = dppf<0x104>(x);   // row_shl:4  -> src[lane+4]
        float b = dppf<0x114>(x);   // row_shr:4  -> src[lane-4]
        return (lane & 4) ? b : a;
    }
    else if constexpr (M == 8) return dppf<0x128>(x);            // row_ror:8 == xor8
    else return __shfl_xor(x, M, 64);
}

template<int W>
__device__ __forceinline__ float exch(float x, int lane) {
    if constexpr (W == 0) return __shfl_xor(x, 32, 64);
    else if constexpr (W == 1) return __shfl_xor(x, 16, 64);
    else if constexpr (W == 2) return lane_xor<8>(x, lane);
    else if constexpr (W == 3) return lane_xor<4>(x, lane);
    else if constexpr (W == 4) return lane_xor<2>(x, lane);
    else return lane_xor<1>(x, lane);
}

__device__ __forceinline__ int qbit(int w, int lane, int j) {
    if (w < 6) return (lane >> (5 - w)) & 1;
    if (w == 6) return (j >> 1) & 1;
    return j & 1;
}

template<int W>
__device__ __forceinline__ void applyU_lane(const float* __restrict__ U, int lane,
                                            float ar[4], float ai[4]) {
    const int b = (lane >> (5 - W)) & 1;
    const float dr  = b ? U[6] : U[0];
    const float di  = b ? U[7] : U[1];
    const float onr = b ? U[4] : U[2];
    const float oni = b ? U[5] : U[3];
    #pragma unroll
    for (int j = 0; j < 4; j++) {
        float br = exch<W>(ar[j], lane);
        float bi = exch<W>(ai[j], lane);
        float nr = dr * ar[j] - di * ai[j] + onr * br - oni * bi;
        float ni = dr * ai[j] + di * ar[j] + onr * bi + oni * br;
        ar[j] = nr; ai[j] = ni;
    }
}

__device__ __forceinline__ void applyU_pair(const float* __restrict__ U,
    float& a0r, float& a0i, float& a1r, float& a1i) {
    float n0r = U[0]*a0r - U[1]*a0i + U[2]*a1r - U[3]*a1i;
    float n0i = U[0]*a0i + U[1]*a0r + U[2]*a1i + U[3]*a1r;
    float n1r = U[4]*a0r - U[5]*a0i + U[6]*a1r - U[7]*a1i;
    float n1i = U[4]*a0i + U[5]*a0r + U[6]*a1i + U[7]*a1r;
    a0r = n0r; a0i = n0i; a1r = n1r; a1i = n1i;
}

__device__ __forceinline__ void applyU_any(int w, const float* __restrict__ U, int lane,
                                           float ar[4], float ai[4]) {
    switch (w) {
        case 0: applyU_lane<0>(U, lane, ar, ai); break;
        case 1: applyU_lane<1>(U, lane, ar, ai); break;
        case 2: applyU_lane<2>(U, lane, ar, ai); break;
        case 3: applyU_lane<3>(U, lane, ar, ai); break;
        case 4: applyU_lane<4>(U, lane, ar, ai); break;
        case 5: applyU_lane<5>(U, lane, ar, ai); break;
        case 6: applyU_pair(U, ar[0], ai[0], ar[2], ai[2]);
                applyU_pair(U, ar[1], ai[1], ar[3], ai[3]); break;
        default:applyU_pair(U, ar[0], ai[0], ar[1], ai[1]);
                applyU_pair(U, ar[2], ai[2], ar[3], ai[3]); break;
    }
}

template<int TW>
__device__ __forceinline__ void cnot_lane(int cw, int lane, float ar[4], float ai[4]) {
    #pragma unroll
    for (int j = 0; j < 4; j++) {
        float br = exch<TW>(ar[j], lane);
        float bi = exch<TW>(ai[j], lane);
        int ctrl = qbit(cw, lane, j);
        ar[j] = ctrl ? br : ar[j];
        ai[j] = ctrl ? bi : ai[j];
    }
}

__device__ __forceinline__ void apply_cnot(int cw, int tw, int lane,
                                           float ar[4], float ai[4]) {
    if (tw < 6) {
        switch (tw) {
            case 0: cnot_lane<0>(cw, lane, ar, ai); break;
            case 1: cnot_lane<1>(cw, lane, ar, ai); break;
            case 2: cnot_lane<2>(cw, lane, ar, ai); break;
            case 3: cnot_lane<3>(cw, lane, ar, ai); break;
            case 4: cnot_lane<4>(cw, lane, ar, ai); break;
            default:cnot_lane<5>(cw, lane, ar, ai); break;
        }
    } else if (tw == 6) {
        int cA = qbit(cw, lane, 0), cB = qbit(cw, lane, 1);
        float n0r = cA ? ar[2] : ar[0], n0i = cA ? ai[2] : ai[0];
        float n2r = cA ? ar[0] : ar[2], n2i = cA ? ai[0] : ai[2];
        float n1r = cB ? ar[3] : ar[1], n1i = cB ? ai[3] : ai[1];
        float n3r = cB ? ar[1] : ar[3], n3i = cB ? ai[1] : ai[3];
        ar[0]=n0r; ai[0]=n0i; ar[1]=n1r; ai[1]=n1i;
        ar[2]=n2r; ai[2]=n2i; ar[3]=n3r; ai[3]=n3i;
    } else {
        int cA = qbit(cw, lane, 0), cB = qbit(cw, lane, 2);
        float n0r = cA ? ar[1] : ar[0], n0i = cA ? ai[1] : ai[0];
        float n1r = cA ? ar[0] : ar[1], n1i = cA ? ai[0] : ai[1];
        float n2r = cB ? ar[3] : ar[2], n2i = cB ? ai[3] : ai[2];
        float n3r = cB ? ar[2] : ar[3], n3i = cB ? ai[2] : ai[3];
        ar[0]=n0r; ai[0]=n0i; ar[1]=n1r; ai[1]=n1i;
        ar[2]=n2r; ai[2]=n2i; ar[3]=n3r; ai[3]=n3i;
    }
}

// DPP all-gather of 8 values within each 8-lane group — validated r5
__device__ __forceinline__ void bcast8(float v, int lane, float h[8]) {
    float p  = lane_xor<1>(v, lane);
    float a0 = (lane & 1) ? p : v;
    float a1 = (lane & 1) ? v : p;
    float q0 = lane_xor<2>(a0, lane);
    float q1 = lane_xor<2>(a1, lane);
    float b0 = (lane & 2) ? q0 : a0;
    float b1 = (lane & 2) ? q1 : a1;
    float b2 = (lane & 2) ? a0 : q0;
    float b3 = (lane & 2) ? a1 : q1;
    float r0 = lane_xor<4>(b0, lane);
    float r1 = lane_xor<4>(b1, lane);
    float r2 = lane_xor<4>(b2, lane);
    float r3 = lane_xor<4>(b3, lane);
    h[0] = (lane & 4) ? r0 : b0;  h[1] = (lane & 4) ? r1 : b1;
    h[2] = (lane & 4) ? r2 : b2;  h[3] = (lane & 4) ? r3 : b3;
    h[4] = (lane & 4) ? b0 : r0;  h[5] = (lane & 4) ? b1 : r1;
    h[6] = (lane & 4) ? b2 : r2;  h[7] = (lane & 4) ? b3 : r3;
}

// ---------------------------------------------------------------------------
// Fused kernel. 256 blocks x 1024 threads; b = blockIdx>>1, half3 = blockIdx&1.
// NOTE: the by-value `circ` kernarg is ONLY ever indexed with compile-time
// constants (unrolled loops / guarded lanes) — runtime indexing forces a
// per-thread scratch copy (~270 MB/dispatch measured in round 5).
// ---------------------------------------------------------------------------
__global__ __launch_bounds__(1024) void k_fused(
    const float* __restrict__ emb,
    const int* __restrict__ sentence,
    const float* __restrict__ Win,
    const float* __restrict__ b_in,
    const float* __restrict__ phi,
    const float* __restrict__ Wout,
    const float* __restrict__ b_out,
    const float* __restrict__ phiq,
    const float* __restrict__ Whead,
    const float* __restrict__ b_head,
    float* __restrict__ out,
    const QCircuit circ)
{
    __shared__ float zxs[S_][32];
    __shared__ float sang[S_][8];
    __shared__ float sF[8][8];
    __shared__ int   sType[MAXG_], sW1[MAXG_], sW2[MAXG_];
    __shared__ float sU[MAXG_][8];
    __shared__ float sInit[8][8];

    const int t     = threadIdx.x;
    const int wave  = t >> 6;
    const int lane  = t & 63;
    const int half  = lane >> 5;
    const int l     = lane & 31;
    const int b     = blockIdx.x >> 1;
    const int half3 = blockIdx.x & 1;

    // circuit -> LDS, compile-time offsets only (thread 0)
    if (t == 0) {
        #pragma unroll
        for (int i = 0; i < MAXG_; i++) {
            sType[i] = circ.type[i];
            sW1[i]   = circ.w1[i];
            sW2[i]   = circ.w2[i];
            #pragma unroll
            for (int j = 0; j < 8; j++) sU[i][j] = circ.U[i][j];
        }
        #pragma unroll
        for (int w = 0; w < 8; w++)
            #pragma unroll
            for (int j = 0; j < 8; j++) sInit[w][j] = circ.initM[w][j];
    }
    // F_w = RX(phiq_w) * endM_w  (lanes 64..71, compile-time w via guards)
    #pragma unroll
    for (int w = 0; w < 8; w++) {
        if (t == 64 + w) {
            float Ew[8];
            #pragma unroll
            for (int k = 0; k < 8; k++) Ew[k] = circ.endM[w][k];
            float ph = phiq[w] * 0.5f;
            float c = __cosf(ph), s = __sinf(ph);
            sF[w][0] =  c*Ew[0] + s*Ew[5];
            sF[w][1] =  c*Ew[1] - s*Ew[4];
            sF[w][2] =  c*Ew[2] + s*Ew[7];
            sF[w][3] =  c*Ew[3] - s*Ew[6];
            sF[w][4] =  s*Ew[1] + c*Ew[4];
            sF[w][5] = -s*Ew[0] + c*Ew[5];
            sF[w][6] =  s*Ew[3] + c*Ew[6];
            sF[w][7] = -s*Ew[2] + c*Ew[7];
        }
    }

    // ---- Phase 1: z_x[s][l] = (b_in+phi)[l] + emb[tok_s] . Win[l,:64] ----
    {
        const float4* w4 = (const float4*)(Win + l * FAN_);
        float wx[64];
        #pragma unroll
        for (int f = 0; f < 16; f++) {
            float4 wv = w4[f];
            wx[4*f+0] = wv.x; wx[4*f+1] = wv.y; wx[4*f+2] = wv.z; wx[4*f+3] = wv.w;
        }
        const float cb = b_in[l] + phi[l];

        #pragma unroll
        for (int i = 0; i < 4; i++) {
            const int s   = wave * 8 + i * 2 + half;
            const int tok = sentence[s * B_ + b];
            const float4* e4 = (const float4*)(emb + tok * E_);
            float z0 = cb, z1 = 0.f, z2 = 0.f, z3 = 0.f;
            #pragma unroll
            for (int f = 0; f < 16; f++) {
                float4 xv = e4[f];
                z0 = fmaf(xv.x, wx[4*f + 0], z0);
                z1 = fmaf(xv.y, wx[4*f + 1], z1);
                z2 = fmaf(xv.z, wx[4*f + 2], z2);
                z3 = fmaf(xv.w, wx[4*f + 3], z3);
            }
            zxs[s][l] = (z0 + z1) + (z2 + z3);
        }
    }
    __syncthreads();

    // ---- Phase 2: serial LSTM scan (lanes 0..31 of wave 0) ----
    if (t < 32) {
        const int g = t >> 3;
        const int h = t & 7;
        const int q = t & 7;
        float wh[8], wo[8];
        #pragma unroll
        for (int k = 0; k < 8; k++) wh[k] = Win[t * FAN_ + 64 + k];
        #pragma unroll
        for (int k = 0; k < 8; k++) wo[k] = Wout[(g * 8 + h) * 8 + k];
        const float bo = b_out[g * 8 + h];

        float hxv[8];
        #pragma unroll
        for (int k = 0; k < 8; k++) hxv[k] = 0.f;
        float cx = 0.f;

        for (int s = 0; s < S_; s++) {
            float z = zxs[s][t];
            #pragma unroll
            for (int k = 0; k < 8; k++) z = fmaf(wh[k], hxv[k], z);

            float qc = __cosf(z);
            // inclusive cumprod over q via DPP row_shr (masked) — validated r5
            float u1 = dppf<0x111>(qc); qc = (q >= 1) ? qc * u1 : qc;
            float u2 = dppf<0x112>(qc); qc = (q >= 2) ? qc * u2 : qc;
            float u4 = dppf<0x114>(qc); qc = (q >= 4) ? qc * u4 : qc;

            // gather all 8 cumprods of this gate-group via DPP
            float qch[8];
            bcast8(qc, t, qch);
            float pre = bo;
            #pragma unroll
            for (int qq = 0; qq < 8; qq++) pre = fmaf(wo[qq], qch[qq], pre);

            // gather pre of all 4 gate groups for this h: xor8 (DPP) + xor16
            float e1 = lane_xor<8>(pre, t);          // group g^1
            float e2 = __shfl_xor(pre, 16, 64);      // group g^2
            float e3 = __shfl_xor(e1, 16, 64);       // group g^3
            float p0 = (g==0)?pre:(g==1)?e1:(g==2)?e2:e3;
            float p1 = (g==1)?pre:(g==0)?e1:(g==3)?e2:e3;
            float p2 = (g==2)?pre:(g==3)?e1:(g==0)?e2:e3;
            float p3 = (g==3)?pre:(g==2)?e1:(g==1)?e2:e3;

            float f_ = sigmoid_f(p0);
            float i_ = sigmoid_f(p1);
            float g_ = tanh_f(p2);
            float o_ = sigmoid_f(p3);
            cx = f_ * cx + i_ * g_;
            float hnew = o_ * tanh_f(cx);

            if (t < 8) sang[s][t] = hnew;
            bcast8(hnew, t, hxv);
        }
    }
    __syncthreads();

    // ---- Phase 3: QFC + measure + head + log_softmax, 4 rows per wave ----
    const int nops = circ.n;   // fixed-offset kernarg read (scalar)
    for (int r = 0; r < 4; r++) {
        const int s = half3 * 64 + wave * 4 + r;

        float ar[4], ai[4];
        {   // init: per-wire v_w = initM[w] . (cos, sin); product state
            float Pr = 1.f, Pi = 0.f;
            float v60r=0,v60i=0,v61r=0,v61i=0,v70r=0,v70i=0,v71r=0,v71i=0;
            #pragma unroll
            for (int w = 0; w < 8; w++) {
                float th = sang[s][w] * 0.5f;
                float c = __cosf(th), sn = __sinf(th);
                const float* M = sInit[w];
                float a0r = M[0]*c + M[2]*sn, a0i = M[1]*c + M[3]*sn;
                float a1r = M[4]*c + M[6]*sn, a1i = M[5]*c + M[7]*sn;
                if (w < 6) {
                    int bit = (lane >> (5 - w)) & 1;
                    float er = bit ? a1r : a0r;
                    float ei = bit ? a1i : a0i;
                    float nr = Pr * er - Pi * ei;
                    float ni = Pr * ei + Pi * er;
                    Pr = nr; Pi = ni;
                } else if (w == 6) { v60r=a0r; v60i=a0i; v61r=a1r; v61i=a1i; }
                else               { v70r=a0r; v70i=a0i; v71r=a1r; v71i=a1i; }
            }
            float t0r = Pr*v60r - Pi*v60i, t0i = Pr*v60i + Pi*v60r;
            float t1r = Pr*v61r - Pi*v61i, t1i = Pr*v61i + Pi*v61r;
            ar[0] = t0r*v70r - t0i*v70i;  ai[0] = t0r*v70i + t0i*v70r;
            ar[1] = t0r*v71r - t0i*v71i;  ai[1] = t0r*v71i + t0i*v71r;
            ar[2] = t1r*v70r - t1i*v70i;  ai[2] = t1r*v70i + t1i*v70r;
            ar[3] = t1r*v71r - t1i*v71i;  ai[3] = t1r*v71i + t1i*v71r;
        }

        for (int i = 0; i < nops; i++) {
            if (sType[i] == 0) applyU_any(sW1[i], sU[i], lane, ar, ai);
            else               apply_cnot(sW1[i], sW2[i], lane, ar, ai);
        }

        #pragma unroll
        for (int w = 0; w < 8; w++)
            applyU_any(w, sF[w], lane, ar, ai);

        // measure <Z_w>: Walsh-Hadamard on pt for lane wires; sums for 6,7
        float p0 = ar[0]*ar[0] + ai[0]*ai[0];
        float p1 = ar[1]*ar[1] + ai[1]*ai[1];
        float p2 = ar[2]*ar[2] + ai[2]*ai[2];
        float p3 = ar[3]*ar[3] + ai[3]*ai[3];
        float pt = p0 + p1 + p2 + p3;
        float a6 = p0 + p1 - p2 - p3;
        float a7 = p0 - p1 + p2 - p3;
        {
            float tv;
            tv = lane_xor<1>(pt, lane);  pt = (lane & 1)  ? (tv - pt) : (tv + pt);
            tv = lane_xor<2>(pt, lane);  pt = (lane & 2)  ? (tv - pt) : (tv + pt);
            tv = lane_xor<4>(pt, lane);  pt = (lane & 4)  ? (tv - pt) : (tv + pt);
            tv = lane_xor<8>(pt, lane);  pt = (lane & 8)  ? (tv - pt) : (tv + pt);
            tv = lane_xor<16>(pt, lane); pt = (lane & 16) ? (tv - pt) : (tv + pt);
            tv = lane_xor<32>(pt, lane); pt = (lane & 32) ? (tv - pt) : (tv + pt);
            a6 += lane_xor<1>(a6, lane);  a6 += lane_xor<2>(a6, lane);
            a6 += lane_xor<4>(a6, lane);  a6 += lane_xor<8>(a6, lane);
            a6 += lane_xor<16>(a6, lane); a6 += lane_xor<32>(a6, lane);
            a7 += lane_xor<1>(a7, lane);  a7 += lane_xor<2>(a7, lane);
            a7 += lane_xor<4>(a7, lane);  a7 += lane_xor<8>(a7, lane);
            a7 += lane_xor<16>(a7, lane); a7 += lane_xor<32>(a7, lane);
        }
        float zl[8];
        zl[0] = __shfl(pt, 32, 64);
        zl[1] = __shfl(pt, 16, 64);
        zl[2] = __shfl(pt, 8, 64);
        zl[3] = __shfl(pt, 4, 64);
        zl[4] = __shfl(pt, 2, 64);
        zl[5] = __shfl(pt, 1, 64);
        zl[6] = a6;
        zl[7] = a7;

        float logit = -1e30f;
        if (lane < T_) {
            logit = b_head[lane];
            #pragma unroll
            for (int w = 0; w < 8; w++)
                logit = fmaf(zl[w], Whead[lane * 8 + w], logit);
        }
        float mx = logit;
        mx = fmaxf(mx, lane_xor<1>(mx, lane));
        mx = fmaxf(mx, lane_xor<2>(mx, lane));
        mx = fmaxf(mx, lane_xor<4>(mx, lane));
        mx = fmaxf(mx, lane_xor<8>(mx, lane));
        float e = (lane < T_) ? __expf(logit - mx) : 0.f;
        float se = e;
        se += lane_xor<1>(se, lane);
        se += lane_xor<2>(se, lane);
        se += lane_xor<4>(se, lane);
        se += lane_xor<8>(se, lane);
        if (lane < T_)
            out[(b * S_ + s) * T_ + lane] = logit - mx - __logf(se);
    }
}

// ---------------------------------------------------------------------------
extern "C" void kernel_launch(void* const* d_in, const int* in_sizes, int n_in,
                              void* d_out, int out_size, void* d_ws, size_t ws_size,
                              hipStream_t stream)
{
    (void)in_sizes; (void)n_in; (void)out_size; (void)d_ws; (void)ws_size;
    const float* emb    = (const float*)d_in[0];
    const float* Win    = (const float*)d_in[1];
    const float* b_in   = (const float*)d_in[2];
    const float* phi    = (const float*)d_in[3];
    const float* Wout   = (const float*)d_in[4];
    const float* b_out  = (const float*)d_in[5];
    const float* phiq   = (const float*)d_in[6];
    const float* Whead  = (const float*)d_in[7];
    const float* b_head = (const float*)d_in[8];
    const int* sentence = (const int*)d_in[9];
    float* out          = (float*)d_out;

    static QCircuit circ = build_circuit();   // deterministic; identical every call

    hipLaunchKernelGGL(k_fused, dim3(2 * B_), dim3(1024), 0, stream,
                       emb, sentence, Win, b_in, phi, Wout, b_out,
                       phiq, Whead, b_head, out, circ);
}

// Round 7
// 234.213 us; speedup vs baseline: 1.0475x; 1.0475x over previous
//
#include <hip/hip_runtime.h>
#include <math.h>
#include <stdint.h>
#include <vector>

#ifndef M_PI
#define M_PI 3.14159265358979323846
#endif

#define S_    128
#define B_    128
#define E_    64
#define H_    8
#define T_    12
#define FAN_  72
#define NOPS_ 30
#define MAXG_ 30

// ---------------------------------------------------------------------------
// numpy.random.RandomState(1234) legacy stream (validated round 4/5/6).
// ---------------------------------------------------------------------------
struct MT19937 {
    uint32_t mt[624];
    int idx;
    void seed(uint32_t s) {
        for (int i = 0; i < 624; i++) {
            mt[i] = s;
            s = 1812433253u * (s ^ (s >> 30)) + (uint32_t)i + 1u;
        }
        idx = 624;
    }
    uint32_t next() {
        if (idx >= 624) {
            for (int i = 0; i < 624; i++) {
                uint32_t y = (mt[i] & 0x80000000u) | (mt[(i + 1) % 624] & 0x7fffffffu);
                uint32_t v = mt[(i + 397) % 624] ^ (y >> 1);
                mt[i] = (y & 1u) ? (v ^ 0x9908b0dfu) : v;
            }
            idx = 0;
        }
        uint32_t y = mt[idx++];
        y ^= y >> 11;
        y ^= (y << 7)  & 0x9d2c5680u;
        y ^= (y << 15) & 0xefc60000u;
        y ^= y >> 18;
        return y;
    }
    uint32_t randint(uint32_t n) {
        uint32_t rng = n - 1u, mask = rng;
        mask |= mask >> 1; mask |= mask >> 2; mask |= mask >> 4;
        mask |= mask >> 8; mask |= mask >> 16;
        uint32_t v;
        do { v = next() & mask; } while (v > rng);
        return v;
    }
    double uniform(double lo, double hi) {
        uint32_t a = next() >> 5, b = next() >> 6;
        double d = ((double)a * 67108864.0 + (double)b) / 9007199254740992.0;
        return lo + (hi - lo) * d;
    }
};

// ---------------------------------------------------------------------------
// Host-side circuit optimizer (validated round 5/6).
// ---------------------------------------------------------------------------
struct C2h { double r, i; };
static inline C2h cmul(C2h a, C2h b) { return { a.r*b.r - a.i*b.i, a.r*b.i + a.i*b.r }; }
static inline C2h cadd(C2h a, C2h b) { return { a.r + b.r, a.i + b.i }; }
struct M22 { C2h m[2][2]; };
static inline M22 mmul(const M22& A, const M22& B) {
    M22 C;
    for (int i = 0; i < 2; i++)
        for (int j = 0; j < 2; j++)
            C.m[i][j] = cadd(cmul(A.m[i][0], B.m[0][j]), cmul(A.m[i][1], B.m[1][j]));
    return C;
}
static inline M22 ident() { return { { { {1,0},{0,0} }, { {0,0},{1,0} } } }; }

struct HostOp { int kind; int a, b; M22 U; };

struct QCircuit {
    int   n;
    int   type[MAXG_];
    int   w1[MAXG_];
    int   w2[MAXG_];
    float U[MAXG_][8];   // [00r,00i,01r,01i,10r,10i,11r,11i]
    float initM[8][8];
    float endM[8][8];
};

static void putM(float* dst, const M22& M) {
    dst[0] = (float)M.m[0][0].r; dst[1] = (float)M.m[0][0].i;
    dst[2] = (float)M.m[0][1].r; dst[3] = (float)M.m[0][1].i;
    dst[4] = (float)M.m[1][0].r; dst[5] = (float)M.m[1][0].i;
    dst[6] = (float)M.m[1][1].r; dst[7] = (float)M.m[1][1].i;
}

static QCircuit build_circuit() {
    MT19937 rng; rng.seed(1234u);
    std::vector<HostOp> raw;
    for (int i = 0; i < NOPS_; i++) {
        uint32_t kind = rng.randint(4);
        if (kind == 3u) {
            int c = (int)rng.randint(8);
            int t = (int)rng.randint(7);
            if (t >= c) t += 1;
            raw.push_back({1, c, t, ident()});
        } else {
            int g = (int)(kind % 3u);
            int w = (int)rng.randint(8);
            double th = rng.uniform(0.0, 2.0 * M_PI);
            double c = cos(0.5 * th), s = sin(0.5 * th);
            M22 M;
            if (g == 0)      M = { { { {c,0},{0,-s} }, { {0,-s},{c,0} } } };   // rx
            else if (g == 1) M = { { { {c,0},{-s,0} }, { {s,0},{c,0} } } };    // ry
            else             M = { { { {c,-s},{0,0} }, { {0,0},{c,s} } } };    // rz
            raw.push_back({0, w, -1, M});
        }
    }

    std::vector<HostOp> items;
    M22 initM[8], endM[8];
    for (int w = 0; w < 8; w++) { initM[w] = ident(); endM[w] = ident(); }

    for (const HostOp& op : raw) {
        if (op.kind == 0) {
            int w = op.a, k = (int)items.size() - 1;
            bool merged = false;
            while (k >= 0) {
                if (items[k].kind == 0) {
                    if (items[k].a == w) { items[k].U = mmul(op.U, items[k].U); merged = true; break; }
                    k--;
                } else {
                    if (w == items[k].a || w == items[k].b) break;
                    k--;
                }
            }
            if (merged) continue;
            if (k < 0) { initM[w] = mmul(op.U, initM[w]); continue; }
            items.push_back(op);
        } else {
            int c = op.a, t = op.b, k = (int)items.size() - 1;
            bool cancelled = false;
            while (k >= 0) {
                if (items[k].kind == 0) {
                    int w = items[k].a;
                    if (w == c || w == t) break;
                    k--;
                } else {
                    int c2 = items[k].a, t2 = items[k].b;
                    if (c2 == c && t2 == t) { items.erase(items.begin() + k); cancelled = true; break; }
                    if (c2 != t && t2 != c) k--;
                    else break;
                }
            }
            if (!cancelled) items.push_back(op);
        }
    }
    bool blocked[8] = {};
    for (int k = (int)items.size() - 1; k >= 0; k--) {
        if (items[k].kind == 0) {
            int w = items[k].a;
            if (!blocked[w]) {
                endM[w] = mmul(endM[w], items[k].U);
                items.erase(items.begin() + k);
            }
        } else {
            blocked[items[k].a] = blocked[items[k].b] = true;
        }
    }

    QCircuit q = {};
    q.n = (int)items.size();
    for (int i = 0; i < q.n; i++) {
        q.type[i] = items[i].kind;
        q.w1[i]   = items[i].a;
        q.w2[i]   = items[i].b;
        putM(q.U[i], items[i].U);
    }
    for (int w = 0; w < 8; w++) { putM(q.initM[w], initM[w]); putM(q.endM[w], endM[w]); }
    return q;
}

// ---------------------------------------------------------------------------
// Device helpers (all validated round 5/6)
// ---------------------------------------------------------------------------
__device__ __forceinline__ float sigmoid_f(float x) { return 1.f / (1.f + __expf(-x)); }
__device__ __forceinline__ float tanh_f(float x) {
    float e = __expf(2.f * x);
    return 1.f - 2.f / (e + 1.f);
}

template<int CTRL>
__device__ __forceinline__ float dppf(float x) {
    union { float f; int i; } u, r;
    u.f = x;
    r.i = __builtin_amdgcn_update_dpp(0, u.i, CTRL, 0xF, 0xF, true);
    return r.f;
}

template<int M>
__device__ __forceinline__ float lane_xor(float x, int lane) {
    if constexpr (M == 1)  return dppf<0xB1>(x);                 // quad_perm [1,0,3,2]
    else if constexpr (M == 2) return dppf<0x4E>(x);             // quad_perm [2,3,0,1]
    else if constexpr (M == 4) {
        float a = dppf<0x104>(x);   // row_shl:4
        float b = dppf<0x114>(x);   // row_shr:4
        return (lane & 4) ? b : a;
    }
    else if constexpr (M == 8) return dppf<0x128>(x);            // row_ror:8 == xor8
    else return __shfl_xor(x, M, 64);
}

template<int W>
__device__ __forceinline__ float exch(float x, int lane) {
    if constexpr (W == 0) return __shfl_xor(x, 32, 64);
    else if constexpr (W == 1) return __shfl_xor(x, 16, 64);
    else if constexpr (W == 2) return lane_xor<8>(x, lane);
    else if constexpr (W == 3) return lane_xor<4>(x, lane);
    else if constexpr (W == 4) return lane_xor<2>(x, lane);
    else return lane_xor<1>(x, lane);
}

__device__ __forceinline__ int qbit(int w, int lane, int j) {
    if (w < 6) return (lane >> (5 - w)) & 1;
    if (w == 6) return (j >> 1) & 1;
    return j & 1;
}

template<int W>
__device__ __forceinline__ void applyU_lane(const float* __restrict__ U, int lane,
                                            float ar[4], float ai[4]) {
    const int b = (lane >> (5 - W)) & 1;
    const float dr  = b ? U[6] : U[0];
    const float di  = b ? U[7] : U[1];
    const float onr = b ? U[4] : U[2];
    const float oni = b ? U[5] : U[3];
    #pragma unroll
    for (int j = 0; j < 4; j++) {
        float br = exch<W>(ar[j], lane);
        float bi = exch<W>(ai[j], lane);
        float nr = dr * ar[j] - di * ai[j] + onr * br - oni * bi;
        float ni = dr * ai[j] + di * ar[j] + onr * bi + oni * br;
        ar[j] = nr; ai[j] = ni;
    }
}

__device__ __forceinline__ void applyU_pair(const float* __restrict__ U,
    float& a0r, float& a0i, float& a1r, float& a1i) {
    float n0r = U[0]*a0r - U[1]*a0i + U[2]*a1r - U[3]*a1i;
    float n0i = U[0]*a0i + U[1]*a0r + U[2]*a1i + U[3]*a1r;
    float n1r = U[4]*a0r - U[5]*a0i + U[6]*a1r - U[7]*a1i;
    float n1i = U[4]*a0i + U[5]*a0r + U[6]*a1i + U[7]*a1r;
    a0r = n0r; a0i = n0i; a1r = n1r; a1i = n1i;
}

__device__ __forceinline__ void applyU_any(int w, const float* __restrict__ U, int lane,
                                           float ar[4], float ai[4]) {
    switch (w) {
        case 0: applyU_lane<0>(U, lane, ar, ai); break;
        case 1: applyU_lane<1>(U, lane, ar, ai); break;
        case 2: applyU_lane<2>(U, lane, ar, ai); break;
        case 3: applyU_lane<3>(U, lane, ar, ai); break;
        case 4: applyU_lane<4>(U, lane, ar, ai); break;
        case 5: applyU_lane<5>(U, lane, ar, ai); break;
        case 6: applyU_pair(U, ar[0], ai[0], ar[2], ai[2]);
                applyU_pair(U, ar[1], ai[1], ar[3], ai[3]); break;
        default:applyU_pair(U, ar[0], ai[0], ar[1], ai[1]);
                applyU_pair(U, ar[2], ai[2], ar[3], ai[3]); break;
    }
}

template<int TW>
__device__ __forceinline__ void cnot_lane(int cw, int lane, float ar[4], float ai[4]) {
    #pragma unroll
    for (int j = 0; j < 4; j++) {
        float br = exch<TW>(ar[j], lane);
        float bi = exch<TW>(ai[j], lane);
        int ctrl = qbit(cw, lane, j);
        ar[j] = ctrl ? br : ar[j];
        ai[j] = ctrl ? bi : ai[j];
    }
}

__device__ __forceinline__ void apply_cnot(int cw, int tw, int lane,
                                           float ar[4], float ai[4]) {
    if (tw < 6) {
        switch (tw) {
            case 0: cnot_lane<0>(cw, lane, ar, ai); break;
            case 1: cnot_lane<1>(cw, lane, ar, ai); break;
            case 2: cnot_lane<2>(cw, lane, ar, ai); break;
            case 3: cnot_lane<3>(cw, lane, ar, ai); break;
            case 4: cnot_lane<4>(cw, lane, ar, ai); break;
            default:cnot_lane<5>(cw, lane, ar, ai); break;
        }
    } else if (tw == 6) {
        int cA = qbit(cw, lane, 0), cB = qbit(cw, lane, 1);
        float n0r = cA ? ar[2] : ar[0], n0i = cA ? ai[2] : ai[0];
        float n2r = cA ? ar[0] : ar[2], n2i = cA ? ai[0] : ai[2];
        float n1r = cB ? ar[3] : ar[1], n1i = cB ? ai[3] : ai[1];
        float n3r = cB ? ar[1] : ar[3], n3i = cB ? ai[1] : ai[3];
        ar[0]=n0r; ai[0]=n0i; ar[1]=n1r; ai[1]=n1i;
        ar[2]=n2r; ai[2]=n2i; ar[3]=n3r; ai[3]=n3i;
    } else {
        int cA = qbit(cw, lane, 0), cB = qbit(cw, lane, 2);
        float n0r = cA ? ar[1] : ar[0], n0i = cA ? ai[1] : ai[0];
        float n1r = cA ? ar[0] : ar[1], n1i = cA ? ai[0] : ai[1];
        float n2r = cB ? ar[3] : ar[2], n2i = cB ? ai[3] : ai[2];
        float n3r = cB ? ar[2] : ar[3], n3i = cB ? ai[2] : ai[3];
        ar[0]=n0r; ai[0]=n0i; ar[1]=n1r; ai[1]=n1i;
        ar[2]=n2r; ai[2]=n2i; ar[3]=n3r; ai[3]=n3i;
    }
}

// DPP all-gather of 8 values within each 8-lane group — validated r5/r6
__device__ __forceinline__ void bcast8(float v, int lane, float h[8]) {
    float p  = lane_xor<1>(v, lane);
    float a0 = (lane & 1) ? p : v;
    float a1 = (lane & 1) ? v : p;
    float q0 = lane_xor<2>(a0, lane);
    float q1 = lane_xor<2>(a1, lane);
    float b0 = (lane & 2) ? q0 : a0;
    float b1 = (lane & 2) ? q1 : a1;
    float b2 = (lane & 2) ? a0 : q0;
    float b3 = (lane & 2) ? a1 : q1;
    float r0 = lane_xor<4>(b0, lane);
    float r1 = lane_xor<4>(b1, lane);
    float r2 = lane_xor<4>(b2, lane);
    float r3 = lane_xor<4>(b3, lane);
    h[0] = (lane & 4) ? r0 : b0;  h[1] = (lane & 4) ? r1 : b1;
    h[2] = (lane & 4) ? r2 : b2;  h[3] = (lane & 4) ? r3 : b3;
    h[4] = (lane & 4) ? b0 : r0;  h[5] = (lane & 4) ? b1 : r1;
    h[6] = (lane & 4) ? b2 : r2;  h[7] = (lane & 4) ? b3 : r3;
}

// ---------------------------------------------------------------------------
// Fused kernel. 256 blocks x 1024 threads; b = blockIdx>>1, half3 = blockIdx&1.
// RULES LEARNED:
//  - by-value kernarg struct: compile-time indexing ONLY (r5: runtime index
//    -> per-thread scratch copy, ~270 MB/dispatch).
//  - NO per-thread array larger than a few regs may stay live across a loop
//    (r6: wx[64] at VGPR_Count=64 -> spill, ~300 MB/dispatch). Phase 1 is
//    restructured: chunked float4 interleave, ~25 live VGPRs.
// ---------------------------------------------------------------------------
__global__ __launch_bounds__(1024) void k_fused(
    const float* __restrict__ emb,
    const int* __restrict__ sentence,
    const float* __restrict__ Win,
    const float* __restrict__ b_in,
    const float* __restrict__ phi,
    const float* __restrict__ Wout,
    const float* __restrict__ b_out,
    const float* __restrict__ phiq,
    const float* __restrict__ Whead,
    const float* __restrict__ b_head,
    float* __restrict__ out,
    const QCircuit circ)
{
    __shared__ float zxs[S_][32];
    __shared__ float sang[S_][8];
    __shared__ float sF[8][8];
    __shared__ int   sType[MAXG_], sW1[MAXG_], sW2[MAXG_];
    __shared__ float sU[MAXG_][8];
    __shared__ float sInit[8][8];

    const int t     = threadIdx.x;
    const int wave  = t >> 6;
    const int lane  = t & 63;
    const int half  = lane >> 5;
    const int l     = lane & 31;
    const int b     = blockIdx.x >> 1;
    const int half3 = blockIdx.x & 1;

    // circuit -> LDS; distributed, compile-time kernarg offsets only
    #pragma unroll
    for (int i = 0; i < MAXG_; i++) {
        if (t == i) {
            sType[i] = circ.type[i];
            sW1[i]   = circ.w1[i];
            sW2[i]   = circ.w2[i];
            #pragma unroll
            for (int j = 0; j < 8; j++) sU[i][j] = circ.U[i][j];
        }
    }
    #pragma unroll
    for (int w = 0; w < 8; w++) {
        if (t == 32 + w) {
            #pragma unroll
            for (int j = 0; j < 8; j++) sInit[w][j] = circ.initM[w][j];
        }
    }
    // F_w = RX(phiq_w) * endM_w  (lanes 64..71, compile-time w via guards)
    #pragma unroll
    for (int w = 0; w < 8; w++) {
        if (t == 64 + w) {
            float Ew[8];
            #pragma unroll
            for (int k = 0; k < 8; k++) Ew[k] = circ.endM[w][k];
            float ph = phiq[w] * 0.5f;
            float c = __cosf(ph), s = __sinf(ph);
            sF[w][0] =  c*Ew[0] + s*Ew[5];
            sF[w][1] =  c*Ew[1] - s*Ew[4];
            sF[w][2] =  c*Ew[2] + s*Ew[7];
            sF[w][3] =  c*Ew[3] - s*Ew[6];
            sF[w][4] =  s*Ew[1] + c*Ew[4];
            sF[w][5] = -s*Ew[0] + c*Ew[5];
            sF[w][6] =  s*Ew[3] + c*Ew[6];
            sF[w][7] = -s*Ew[2] + c*Ew[7];
        }
    }

    // ---- Phase 1: z_x[s][l] = (b_in+phi)[l] + emb[tok_s] . Win[l,:64] ----
    // Chunked interleave: 16 x float4 of Win vs 4 steps' emb chunks.
    // Max ~25 live VGPRs; nothing spillable.
    {
        const float4* w4 = (const float4*)(Win + l * FAN_);
        const float cb = b_in[l] + phi[l];

        const float4* e4_0;
        const float4* e4_1;
        const float4* e4_2;
        const float4* e4_3;
        {
            const int s0 = wave * 8 + 0 * 2 + half;
            const int s1 = wave * 8 + 1 * 2 + half;
            const int s2 = wave * 8 + 2 * 2 + half;
            const int s3 = wave * 8 + 3 * 2 + half;
            e4_0 = (const float4*)(emb + sentence[s0 * B_ + b] * E_);
            e4_1 = (const float4*)(emb + sentence[s1 * B_ + b] * E_);
            e4_2 = (const float4*)(emb + sentence[s2 * B_ + b] * E_);
            e4_3 = (const float4*)(emb + sentence[s3 * B_ + b] * E_);
        }
        float a0 = cb, a1 = cb, a2 = cb, a3 = cb;
        #pragma unroll
        for (int f = 0; f < 16; f++) {
            float4 wv = w4[f];
            float4 x0 = e4_0[f];
            float4 x1 = e4_1[f];
            float4 x2 = e4_2[f];
            float4 x3 = e4_3[f];
            a0 = fmaf(x0.x, wv.x, a0); a0 = fmaf(x0.y, wv.y, a0);
            a0 = fmaf(x0.z, wv.z, a0); a0 = fmaf(x0.w, wv.w, a0);
            a1 = fmaf(x1.x, wv.x, a1); a1 = fmaf(x1.y, wv.y, a1);
            a1 = fmaf(x1.z, wv.z, a1); a1 = fmaf(x1.w, wv.w, a1);
            a2 = fmaf(x2.x, wv.x, a2); a2 = fmaf(x2.y, wv.y, a2);
            a2 = fmaf(x2.z, wv.z, a2); a2 = fmaf(x2.w, wv.w, a2);
            a3 = fmaf(x3.x, wv.x, a3); a3 = fmaf(x3.y, wv.y, a3);
            a3 = fmaf(x3.z, wv.z, a3); a3 = fmaf(x3.w, wv.w, a3);
        }
        zxs[wave * 8 + 0 + half][l] = a0;
        zxs[wave * 8 + 2 + half][l] = a1;
        zxs[wave * 8 + 4 + half][l] = a2;
        zxs[wave * 8 + 6 + half][l] = a3;
    }
    __syncthreads();

    // ---- Phase 2: serial LSTM scan (lanes 0..31 of wave 0) ----
    if (t < 32) {
        const int g = t >> 3;
        const int h = t & 7;
        const int q = t & 7;
        float wh[8], wo[8];
        #pragma unroll
        for (int k = 0; k < 8; k++) wh[k] = Win[t * FAN_ + 64 + k];
        #pragma unroll
        for (int k = 0; k < 8; k++) wo[k] = Wout[(g * 8 + h) * 8 + k];
        const float bo = b_out[g * 8 + h];

        float hxv[8];
        #pragma unroll
        for (int k = 0; k < 8; k++) hxv[k] = 0.f;
        float cx = 0.f;

        for (int s = 0; s < S_; s++) {
            float z = zxs[s][t];
            #pragma unroll
            for (int k = 0; k < 8; k++) z = fmaf(wh[k], hxv[k], z);

            float qc = __cosf(z);
            float u1 = dppf<0x111>(qc); qc = (q >= 1) ? qc * u1 : qc;
            float u2 = dppf<0x112>(qc); qc = (q >= 2) ? qc * u2 : qc;
            float u4 = dppf<0x114>(qc); qc = (q >= 4) ? qc * u4 : qc;

            float qch[8];
            bcast8(qc, t, qch);
            float pre = bo;
            #pragma unroll
            for (int qq = 0; qq < 8; qq++) pre = fmaf(wo[qq], qch[qq], pre);

            float e1 = lane_xor<8>(pre, t);          // group g^1
            float e2 = __shfl_xor(pre, 16, 64);      // group g^2
            float e3 = __shfl_xor(e1, 16, 64);       // group g^3
            float p0 = (g==0)?pre:(g==1)?e1:(g==2)?e2:e3;
            float p1 = (g==1)?pre:(g==0)?e1:(g==3)?e2:e3;
            float p2 = (g==2)?pre:(g==3)?e1:(g==0)?e2:e3;
            float p3 = (g==3)?pre:(g==2)?e1:(g==1)?e2:e3;

            float f_ = sigmoid_f(p0);
            float i_ = sigmoid_f(p1);
            float g_ = tanh_f(p2);
            float o_ = sigmoid_f(p3);
            cx = f_ * cx + i_ * g_;
            float hnew = o_ * tanh_f(cx);

            if (t < 8) sang[s][t] = hnew;
            bcast8(hnew, t, hxv);
        }
    }
    __syncthreads();

    // ---- Phase 3: QFC + measure + head + log_softmax, 4 rows per wave ----
    const int nops = circ.n;
    for (int r = 0; r < 4; r++) {
        const int s = half3 * 64 + wave * 4 + r;

        float ar[4], ai[4];
        {   // init: per-wire v_w = initM[w] . (cos, sin); product state
            float Pr = 1.f, Pi = 0.f;
            float v60r=0,v60i=0,v61r=0,v61i=0,v70r=0,v70i=0,v71r=0,v71i=0;
            #pragma unroll
            for (int w = 0; w < 8; w++) {
                float th = sang[s][w] * 0.5f;
                float c = __cosf(th), sn = __sinf(th);
                const float* M = sInit[w];
                float a0r = M[0]*c + M[2]*sn, a0i = M[1]*c + M[3]*sn;
                float a1r = M[4]*c + M[6]*sn, a1i = M[5]*c + M[7]*sn;
                if (w < 6) {
                    int bit = (lane >> (5 - w)) & 1;
                    float er = bit ? a1r : a0r;
                    float ei = bit ? a1i : a0i;
                    float nr = Pr * er - Pi * ei;
                    float ni = Pr * ei + Pi * er;
                    Pr = nr; Pi = ni;
                } else if (w == 6) { v60r=a0r; v60i=a0i; v61r=a1r; v61i=a1i; }
                else               { v70r=a0r; v70i=a0i; v71r=a1r; v71i=a1i; }
            }
            float t0r = Pr*v60r - Pi*v60i, t0i = Pr*v60i + Pi*v60r;
            float t1r = Pr*v61r - Pi*v61i, t1i = Pr*v61i + Pi*v61r;
            ar[0] = t0r*v70r - t0i*v70i;  ai[0] = t0r*v70i + t0i*v70r;
            ar[1] = t0r*v71r - t0i*v71i;  ai[1] = t0r*v71i + t0i*v71r;
            ar[2] = t1r*v70r - t1i*v70i;  ai[2] = t1r*v70i + t1i*v70r;
            ar[3] = t1r*v71r - t1i*v71i;  ai[3] = t1r*v71i + t1i*v71r;
        }

        for (int i = 0; i < nops; i++) {
            if (sType[i] == 0) applyU_any(sW1[i], sU[i], lane, ar, ai);
            else               apply_cnot(sW1[i], sW2[i], lane, ar, ai);
        }

        #pragma unroll
        for (int w = 0; w < 8; w++)
            applyU_any(w, sF[w], lane, ar, ai);

        // measure <Z_w>: Walsh-Hadamard on pt for lane wires; sums for 6,7
        float p0 = ar[0]*ar[0] + ai[0]*ai[0];
        float p1 = ar[1]*ar[1] + ai[1]*ai[1];
        float p2 = ar[2]*ar[2] + ai[2]*ai[2];
        float p3 = ar[3]*ar[3] + ai[3]*ai[3];
        float pt = p0 + p1 + p2 + p3;
        float a6 = p0 + p1 - p2 - p3;
        float a7 = p0 - p1 + p2 - p3;
        {
            float tv;
            tv = lane_xor<1>(pt, lane);  pt = (lane & 1)  ? (tv - pt) : (tv + pt);
            tv = lane_xor<2>(pt, lane);  pt = (lane & 2)  ? (tv - pt) : (tv + pt);
            tv = lane_xor<4>(pt, lane);  pt = (lane & 4)  ? (tv - pt) : (tv + pt);
            tv = lane_xor<8>(pt, lane);  pt = (lane & 8)  ? (tv - pt) : (tv + pt);
            tv = lane_xor<16>(pt, lane); pt = (lane & 16) ? (tv - pt) : (tv + pt);
            tv = lane_xor<32>(pt, lane); pt = (lane & 32) ? (tv - pt) : (tv + pt);
            a6 += lane_xor<1>(a6, lane);  a6 += lane_xor<2>(a6, lane);
            a6 += lane_xor<4>(a6, lane);  a6 += lane_xor<8>(a6, lane);
            a6 += lane_xor<16>(a6, lane); a6 += lane_xor<32>(a6, lane);
            a7 += lane_xor<1>(a7, lane);  a7 += lane_xor<2>(a7, lane);
            a7 += lane_xor<4>(a7, lane);  a7 += lane_xor<8>(a7, lane);
            a7 += lane_xor<16>(a7, lane); a7 += lane_xor<32>(a7, lane);
        }
        float zl[8];
        zl[0] = __shfl(pt, 32, 64);
        zl[1] = __shfl(pt, 16, 64);
        zl[2] = __shfl(pt, 8, 64);
        zl[3] = __shfl(pt, 4, 64);
        zl[4] = __shfl(pt, 2, 64);
        zl[5] = __shfl(pt, 1, 64);
        zl[6] = a6;
        zl[7] = a7;

        float logit = -1e30f;
        if (lane < T_) {
            logit = b_head[lane];
            #pragma unroll
            for (int w = 0; w < 8; w++)
                logit = fmaf(zl[w], Whead[lane * 8 + w], logit);
        }
        float mx = logit;
        mx = fmaxf(mx, lane_xor<1>(mx, lane));
        mx = fmaxf(mx, lane_xor<2>(mx, lane));
        mx = fmaxf(mx, lane_xor<4>(mx, lane));
        mx = fmaxf(mx, lane_xor<8>(mx, lane));
        float e = (lane < T_) ? __expf(logit - mx) : 0.f;
        float se = e;
        se += lane_xor<1>(se, lane);
        se += lane_xor<2>(se, lane);
        se += lane_xor<4>(se, lane);
        se += lane_xor<8>(se, lane);
        if (lane < T_)
            out[(b * S_ + s) * T_ + lane] = logit - mx - __logf(se);
    }
}

// ---------------------------------------------------------------------------
extern "C" void kernel_launch(void* const* d_in, const int* in_sizes, int n_in,
                              void* d_out, int out_size, void* d_ws, size_t ws_size,
                              hipStream_t stream)
{
    (void)in_sizes; (void)n_in; (void)out_size; (void)d_ws; (void)ws_size;
    const float* emb    = (const float*)d_in[0];
    const float* Win    = (const float*)d_in[1];
    const float* b_in   = (const float*)d_in[2];
    const float* phi    = (const float*)d_in[3];
    const float* Wout   = (const float*)d_in[4];
    const float* b_out  = (const float*)d_in[5];
    const float* phiq   = (const float*)d_in[6];
    const float* Whead  = (const float*)d_in[7];
    const float* b_head = (const float*)d_in[8];
    const int* sentence = (const int*)d_in[9];
    float* out          = (float*)d_out;

    static QCircuit circ = build_circuit();   // deterministic; identical every call

    hipLaunchKernelGGL(k_fused, dim3(2 * B_), dim3(1024), 0, stream,
                       emb, sentence, Win, b_in, phi, Wout, b_out,
                       phiq, Whead, b_head, out, circ);
}

// Round 8
// 172.185 us; speedup vs baseline: 1.4248x; 1.3602x over previous
//
#include <hip/hip_runtime.h>
#include <math.h>
#include <stdint.h>

#define S_    128
#define B_    128
#define E_    64
#define H_    8
#define T_    12
#define FAN_  72
#define NOPS_ 30
#define MAXG_ 30

// ===========================================================================
// COMPILE-TIME circuit construction.
// numpy.random.RandomState(1234) legacy stream (validated r4-r7) + the
// circuit optimizer (validated r5-r7), all constexpr so the final gate list
// becomes literal constants in the kernel — no kernarg struct, no LDS
// tables, no per-gate register pressure from loaded coefficients.
// ===========================================================================
constexpr double CT_PI = 3.14159265358979323846;

constexpr double ct_cos(double x) {   // |x| <= pi here; Taylor, double-exact
    double t = 1.0, s = 1.0, x2 = x * x;
    for (int k = 1; k <= 20; k++) { t *= -x2 / ((2.0*k - 1.0) * (2.0*k)); s += t; }
    return s;
}
constexpr double ct_sin(double x) {
    double t = x, s = x, x2 = x * x;
    for (int k = 1; k <= 20; k++) { t *= -x2 / ((2.0*k) * (2.0*k + 1.0)); s += t; }
    return s;
}

// complex 2x2: [00r,00i,01r,01i,10r,10i,11r,11i]
constexpr void ct_mmul(const double* A, const double* B, double* C) {
    for (int i = 0; i < 2; i++)
        for (int j = 0; j < 2; j++) {
            double rr = 0.0, ii = 0.0;
            for (int k = 0; k < 2; k++) {
                double ar = A[(i*2+k)*2], ai = A[(i*2+k)*2+1];
                double br = B[(k*2+j)*2], bi = B[(k*2+j)*2+1];
                rr += ar*br - ai*bi;
                ii += ar*bi + ai*br;
            }
            C[(i*2+j)*2] = rr; C[(i*2+j)*2+1] = ii;
        }
}

struct CTC {
    int n;
    int type[MAXG_];      // 0 gate1, 1 cnot
    int w1[MAXG_];        // wire / control
    int w2[MAXG_];        // target
    double U[MAXG_][8];
    double initM[8][8];
    double endM[8][8];
};

constexpr CTC build_ct() {
    // --- MT19937, seed 1234 ---
    uint32_t mt[624] = {};
    int idx = 624;
    {
        uint32_t s = 1234u;
        for (int i = 0; i < 624; i++) {
            mt[i] = s;
            s = 1812433253u * (s ^ (s >> 30)) + (uint32_t)i + 1u;
        }
    }
    auto nextf = [&]() -> uint32_t {
        if (idx >= 624) {
            for (int i = 0; i < 624; i++) {
                uint32_t y = (mt[i] & 0x80000000u) | (mt[(i+1)%624] & 0x7fffffffu);
                uint32_t v = mt[(i+397)%624] ^ (y >> 1);
                mt[i] = (y & 1u) ? (v ^ 0x9908b0dfu) : v;
            }
            idx = 0;
        }
        uint32_t y = mt[idx++];
        y ^= y >> 11;
        y ^= (y << 7)  & 0x9d2c5680u;
        y ^= (y << 15) & 0xefc60000u;
        y ^= y >> 18;
        return y;
    };
    auto randint = [&](uint32_t n) -> uint32_t {
        uint32_t rng = n - 1u, mask = rng;
        mask |= mask >> 1; mask |= mask >> 2; mask |= mask >> 4;
        mask |= mask >> 8; mask |= mask >> 16;
        uint32_t v = 0;
        do { v = nextf() & mask; } while (v > rng);
        return v;
    };
    auto uniform2pi = [&]() -> double {
        uint32_t a = nextf() >> 5;
        uint32_t b = nextf() >> 6;
        double d = ((double)a * 67108864.0 + (double)b) / 9007199254740992.0;
        return 2.0 * CT_PI * d;
    };

    // --- raw op generation (validated) ---
    int kindA[NOPS_] = {}, aA[NOPS_] = {}, bA[NOPS_] = {};
    double UA[NOPS_][8] = {};
    for (int i = 0; i < NOPS_; i++) {
        uint32_t kind = randint(4);
        if (kind == 3u) {
            int c = (int)randint(8);
            int t = (int)randint(7);
            if (t >= c) t += 1;
            kindA[i] = 1; aA[i] = c; bA[i] = t;
            UA[i][0] = 1.0; UA[i][6] = 1.0;
        } else {
            int g = (int)(kind % 3u);
            int w = (int)randint(8);
            double th = uniform2pi();
            double c = ct_cos(0.5 * th), s = ct_sin(0.5 * th);
            kindA[i] = 0; aA[i] = w; bA[i] = -1;
            if (g == 0)      { UA[i][0]=c;  UA[i][3]=-s; UA[i][5]=-s; UA[i][6]=c; }            // rx
            else if (g == 1) { UA[i][0]=c;  UA[i][2]=-s; UA[i][4]= s; UA[i][6]=c; }            // ry
            else             { UA[i][0]=c;  UA[i][1]=-s; UA[i][6]= c; UA[i][7]=s; }            // rz
        }
    }

    // --- optimizer (validated): merge, leading-fold, cnot-cancel, trailing ---
    int ikind[MAXG_] = {}, ia[MAXG_] = {}, ib[MAXG_] = {};
    double iU[MAXG_][8] = {};
    int cnt = 0;
    double initM[8][8] = {}, endM[8][8] = {};
    for (int w = 0; w < 8; w++) { initM[w][0] = 1.0; initM[w][6] = 1.0;
                                  endM[w][0]  = 1.0; endM[w][6]  = 1.0; }

    for (int oi = 0; oi < NOPS_; oi++) {
        if (kindA[oi] == 0) {
            int w = aA[oi], k = cnt - 1;
            bool merged = false;
            while (k >= 0) {
                if (ikind[k] == 0) {
                    if (ia[k] == w) {
                        double tmp[8] = {};
                        ct_mmul(UA[oi], iU[k], tmp);
                        for (int j = 0; j < 8; j++) iU[k][j] = tmp[j];
                        merged = true; break;
                    }
                    k--;
                } else {
                    if (w == ia[k] || w == ib[k]) break;
                    k--;
                }
            }
            if (merged) continue;
            if (k < 0) {
                double tmp[8] = {};
                ct_mmul(UA[oi], initM[w], tmp);
                for (int j = 0; j < 8; j++) initM[w][j] = tmp[j];
                continue;
            }
            ikind[cnt] = 0; ia[cnt] = w; ib[cnt] = -1;
            for (int j = 0; j < 8; j++) iU[cnt][j] = UA[oi][j];
            cnt++;
        } else {
            int c = aA[oi], t2 = bA[oi], k = cnt - 1;
            bool cancelled = false;
            while (k >= 0) {
                if (ikind[k] == 0) {
                    int w = ia[k];
                    if (w == c || w == t2) break;
                    k--;
                } else {
                    int c2 = ia[k], tt = ib[k];
                    if (c2 == c && tt == t2) {
                        for (int m = k; m < cnt - 1; m++) {
                            ikind[m] = ikind[m+1]; ia[m] = ia[m+1]; ib[m] = ib[m+1];
                            for (int j = 0; j < 8; j++) iU[m][j] = iU[m+1][j];
                        }
                        cnt--; cancelled = true; break;
                    }
                    if (c2 != t2 && tt != c) k--;
                    else break;
                }
            }
            if (!cancelled) {
                ikind[cnt] = 1; ia[cnt] = c; ib[cnt] = t2;
                for (int j = 0; j < 8; j++) iU[cnt][j] = 0.0;
                iU[cnt][0] = 1.0; iU[cnt][6] = 1.0;
                cnt++;
            }
        }
    }
    bool blocked[8] = {};
    for (int k = cnt - 1; k >= 0; k--) {
        if (ikind[k] == 0) {
            int w = ia[k];
            if (!blocked[w]) {
                double tmp[8] = {};
                ct_mmul(endM[w], iU[k], tmp);
                for (int j = 0; j < 8; j++) endM[w][j] = tmp[j];
                for (int m = k; m < cnt - 1; m++) {
                    ikind[m] = ikind[m+1]; ia[m] = ia[m+1]; ib[m] = ib[m+1];
                    for (int j = 0; j < 8; j++) iU[m][j] = iU[m+1][j];
                }
                cnt--;
            }
        } else {
            blocked[ia[k]] = true; blocked[ib[k]] = true;
        }
    }

    CTC q = {};
    q.n = cnt;
    for (int i = 0; i < cnt; i++) {
        q.type[i] = ikind[i]; q.w1[i] = ia[i]; q.w2[i] = ib[i];
        for (int j = 0; j < 8; j++) q.U[i][j] = iU[i][j];
    }
    for (int w = 0; w < 8; w++)
        for (int j = 0; j < 8; j++) { q.initM[w][j] = initM[w][j]; q.endM[w][j] = endM[w][j]; }
    return q;
}

constexpr CTC CIRC = build_ct();

// ===========================================================================
// Device helpers (DPP cross-lane, validated r5-r7)
// ===========================================================================
__device__ __forceinline__ float sigmoid_f(float x) { return 1.f / (1.f + __expf(-x)); }
__device__ __forceinline__ float tanh_f(float x) {
    float e = __expf(2.f * x);
    return 1.f - 2.f / (e + 1.f);
}

template<int CTRL>
__device__ __forceinline__ float dppf(float x) {
    union { float f; int i; } u, r;
    u.f = x;
    r.i = __builtin_amdgcn_update_dpp(0, u.i, CTRL, 0xF, 0xF, true);
    return r.f;
}

template<int M>
__device__ __forceinline__ float lane_xor(float x, int lane) {
    if constexpr (M == 1)  return dppf<0xB1>(x);
    else if constexpr (M == 2) return dppf<0x4E>(x);
    else if constexpr (M == 4) {
        float a = dppf<0x104>(x);
        float b = dppf<0x114>(x);
        return (lane & 4) ? b : a;
    }
    else if constexpr (M == 8) return dppf<0x128>(x);
    else return __shfl_xor(x, M, 64);
}

template<int W>
__device__ __forceinline__ float exch(float x, int lane) {
    if constexpr (W == 0) return __shfl_xor(x, 32, 64);
    else if constexpr (W == 1) return __shfl_xor(x, 16, 64);
    else if constexpr (W == 2) return lane_xor<8>(x, lane);
    else if constexpr (W == 3) return lane_xor<4>(x, lane);
    else if constexpr (W == 4) return lane_xor<2>(x, lane);
    else return lane_xor<1>(x, lane);
}

template<int W>
__device__ __forceinline__ int qbit_ct(int lane, int j) {
    if constexpr (W < 6) return (lane >> (5 - W)) & 1;
    else if constexpr (W == 6) return (j >> 1) & 1;
    else return j & 1;
}

// generic gate, runtime coefficients, compile-time wire
__device__ __forceinline__ void pair_rt(float u0, float u1, float u2, float u3,
                                        float u4, float u5, float u6, float u7,
                                        float& a0r, float& a0i, float& a1r, float& a1i) {
    float n0r = u0*a0r - u1*a0i + u2*a1r - u3*a1i;
    float n0i = u0*a0i + u1*a0r + u2*a1i + u3*a1r;
    float n1r = u4*a0r - u5*a0i + u6*a1r - u7*a1i;
    float n1i = u4*a0i + u5*a0r + u6*a1i + u7*a1r;
    a0r = n0r; a0i = n0i; a1r = n1r; a1i = n1i;
}

template<int W>
__device__ __forceinline__ void gate_rt(float u0, float u1, float u2, float u3,
                                        float u4, float u5, float u6, float u7,
                                        int lane, float ar[4], float ai[4]) {
    if constexpr (W < 6) {
        const int b = (lane >> (5 - W)) & 1;
        const float dr  = b ? u6 : u0;
        const float di  = b ? u7 : u1;
        const float onr = b ? u4 : u2;
        const float oni = b ? u5 : u3;
        #pragma unroll
        for (int j = 0; j < 4; j++) {
            float br = exch<W>(ar[j], lane);
            float bi = exch<W>(ai[j], lane);
            float nr = dr * ar[j] - di * ai[j] + onr * br - oni * bi;
            float ni = dr * ai[j] + di * ar[j] + onr * bi + oni * br;
            ar[j] = nr; ai[j] = ni;
        }
    } else if constexpr (W == 6) {
        pair_rt(u0,u1,u2,u3,u4,u5,u6,u7, ar[0], ai[0], ar[2], ai[2]);
        pair_rt(u0,u1,u2,u3,u4,u5,u6,u7, ar[1], ai[1], ar[3], ai[3]);
    } else {
        pair_rt(u0,u1,u2,u3,u4,u5,u6,u7, ar[0], ai[0], ar[1], ai[1]);
        pair_rt(u0,u1,u2,u3,u4,u5,u6,u7, ar[2], ai[2], ar[3], ai[3]);
    }
}

template<int CW, int TW>
__device__ __forceinline__ void cnot_ct(int lane, float ar[4], float ai[4]) {
    if constexpr (TW < 6) {
        #pragma unroll
        for (int j = 0; j < 4; j++) {
            float br = exch<TW>(ar[j], lane);
            float bi = exch<TW>(ai[j], lane);
            int ctrl = qbit_ct<CW>(lane, j);
            ar[j] = ctrl ? br : ar[j];
            ai[j] = ctrl ? bi : ai[j];
        }
    } else if constexpr (TW == 6) {
        int cA = qbit_ct<CW>(lane, 0), cB = qbit_ct<CW>(lane, 1);
        float n0r = cA ? ar[2] : ar[0], n0i = cA ? ai[2] : ai[0];
        float n2r = cA ? ar[0] : ar[2], n2i = cA ? ai[0] : ai[2];
        float n1r = cB ? ar[3] : ar[1], n1i = cB ? ai[3] : ai[1];
        float n3r = cB ? ar[1] : ar[3], n3i = cB ? ai[1] : ai[3];
        ar[0]=n0r; ai[0]=n0i; ar[1]=n1r; ai[1]=n1i;
        ar[2]=n2r; ai[2]=n2i; ar[3]=n3r; ai[3]=n3i;
    } else {
        int cA = qbit_ct<CW>(lane, 0), cB = qbit_ct<CW>(lane, 2);
        float n0r = cA ? ar[1] : ar[0], n0i = cA ? ai[1] : ai[0];
        float n1r = cA ? ar[0] : ar[1], n1i = cA ? ai[0] : ai[1];
        float n2r = cB ? ar[3] : ar[2], n2i = cB ? ai[3] : ai[2];
        float n3r = cB ? ar[2] : ar[3], n3i = cB ? ai[2] : ai[3];
        ar[0]=n0r; ai[0]=n0i; ar[1]=n1r; ai[1]=n1i;
        ar[2]=n2r; ai[2]=n2i; ar[3]=n3r; ai[3]=n3i;
    }
}

// one constexpr gate op: all coefficients fold to float literals
template<int I>
__device__ __forceinline__ void gate_op(int lane, float ar[4], float ai[4]) {
    constexpr int w = CIRC.w1[I];
    constexpr float u0 = (float)CIRC.U[I][0], u1 = (float)CIRC.U[I][1];
    constexpr float u2 = (float)CIRC.U[I][2], u3 = (float)CIRC.U[I][3];
    constexpr float u4 = (float)CIRC.U[I][4], u5 = (float)CIRC.U[I][5];
    constexpr float u6 = (float)CIRC.U[I][6], u7 = (float)CIRC.U[I][7];
    gate_rt<w>(u0,u1,u2,u3,u4,u5,u6,u7, lane, ar, ai);
}

template<int I>
__device__ __forceinline__ void run_ops(int lane, float ar[4], float ai[4]) {
    if constexpr (I < CIRC.n) {
        if constexpr (CIRC.type[I] == 0) gate_op<I>(lane, ar, ai);
        else cnot_ct<CIRC.w1[I], CIRC.w2[I]>(lane, ar, ai);
        run_ops<I + 1>(lane, ar, ai);
    }
}

// per-wire init vector: v = initM[W] . (cos(th), sin(th)) with literal initM
struct V2 { float r0, i0, r1, i1; };
template<int W>
__device__ __forceinline__ V2 init_wire(float th) {
    constexpr float m0 = (float)CIRC.initM[W][0], m1 = (float)CIRC.initM[W][1];
    constexpr float m2 = (float)CIRC.initM[W][2], m3 = (float)CIRC.initM[W][3];
    constexpr float m4 = (float)CIRC.initM[W][4], m5 = (float)CIRC.initM[W][5];
    constexpr float m6 = (float)CIRC.initM[W][6], m7 = (float)CIRC.initM[W][7];
    float c = __cosf(th), s = __sinf(th);
    V2 v;
    v.r0 = m0*c + m2*s; v.i0 = m1*c + m3*s;
    v.r1 = m4*c + m6*s; v.i1 = m5*c + m7*s;
    return v;
}

// trailing: F_W = RX(phiq_W) * endM_W (endM literal, c/s runtime) then apply
template<int W>
__device__ __forceinline__ void final_wire(float c, float s, int lane,
                                           float ar[4], float ai[4]) {
    constexpr float E0 = (float)CIRC.endM[W][0], E1 = (float)CIRC.endM[W][1];
    constexpr float E2 = (float)CIRC.endM[W][2], E3 = (float)CIRC.endM[W][3];
    constexpr float E4 = (float)CIRC.endM[W][4], E5 = (float)CIRC.endM[W][5];
    constexpr float E6 = (float)CIRC.endM[W][6], E7 = (float)CIRC.endM[W][7];
    float F0 =  c*E0 + s*E5;
    float F1 =  c*E1 - s*E4;
    float F2 =  c*E2 + s*E7;
    float F3 =  c*E3 - s*E6;
    float F4 =  s*E1 + c*E4;
    float F5 = -s*E0 + c*E5;
    float F6 =  s*E3 + c*E6;
    float F7 = -s*E2 + c*E7;
    gate_rt<W>(F0,F1,F2,F3,F4,F5,F6,F7, lane, ar, ai);
}

// DPP all-gather of 8 values within each 8-lane group — validated r5-r7
__device__ __forceinline__ void bcast8(float v, int lane, float h[8]) {
    float p  = lane_xor<1>(v, lane);
    float a0 = (lane & 1) ? p : v;
    float a1 = (lane & 1) ? v : p;
    float q0 = lane_xor<2>(a0, lane);
    float q1 = lane_xor<2>(a1, lane);
    float b0 = (lane & 2) ? q0 : a0;
    float b1 = (lane & 2) ? q1 : a1;
    float b2 = (lane & 2) ? a0 : q0;
    float b3 = (lane & 2) ? a1 : q1;
    float r0 = lane_xor<4>(b0, lane);
    float r1 = lane_xor<4>(b1, lane);
    float r2 = lane_xor<4>(b2, lane);
    float r3 = lane_xor<4>(b3, lane);
    h[0] = (lane & 4) ? r0 : b0;  h[1] = (lane & 4) ? r1 : b1;
    h[2] = (lane & 4) ? r2 : b2;  h[3] = (lane & 4) ? r3 : b3;
    h[4] = (lane & 4) ? b0 : r0;  h[5] = (lane & 4) ? b1 : r1;
    h[6] = (lane & 4) ? b2 : r2;  h[7] = (lane & 4) ? b3 : r3;
}

// ===========================================================================
// Fused kernel. 256 blocks x 1024 threads; b = blockIdx>>1, half3 = blockIdx&1.
// Phase 3 is a fully template-unrolled constexpr circuit: no kernarg struct,
// no LDS gate tables, literal coefficients (minimal register pressure).
// ===========================================================================
__global__ __launch_bounds__(1024) void k_fused(
    const float* __restrict__ emb,
    const int* __restrict__ sentence,
    const float* __restrict__ Win,
    const float* __restrict__ b_in,
    const float* __restrict__ phi,
    const float* __restrict__ Wout,
    const float* __restrict__ b_out,
    const float* __restrict__ phiq,
    const float* __restrict__ Whead,
    const float* __restrict__ b_head,
    float* __restrict__ out)
{
    __shared__ float zxs[S_][32];
    __shared__ float sang[S_][8];

    const int t     = threadIdx.x;
    const int wave  = t >> 6;
    const int lane  = t & 63;
    const int half  = lane >> 5;
    const int l     = lane & 31;
    const int b     = blockIdx.x >> 1;
    const int half3 = blockIdx.x & 1;

    // ---- Phase 1: z_x[s][l] = (b_in+phi)[l] + emb[tok_s] . Win[l,:64] ----
    // Chunked float4 interleave; ~25 live VGPRs (r7, validated).
    {
        const float4* w4 = (const float4*)(Win + l * FAN_);
        const float cb = b_in[l] + phi[l];

        const float4* e4_0;
        const float4* e4_1;
        const float4* e4_2;
        const float4* e4_3;
        {
            const int s0 = wave * 8 + 0 + half;
            const int s1 = wave * 8 + 2 + half;
            const int s2 = wave * 8 + 4 + half;
            const int s3 = wave * 8 + 6 + half;
            e4_0 = (const float4*)(emb + sentence[s0 * B_ + b] * E_);
            e4_1 = (const float4*)(emb + sentence[s1 * B_ + b] * E_);
            e4_2 = (const float4*)(emb + sentence[s2 * B_ + b] * E_);
            e4_3 = (const float4*)(emb + sentence[s3 * B_ + b] * E_);
        }
        float a0 = cb, a1 = cb, a2 = cb, a3 = cb;
        #pragma unroll
        for (int f = 0; f < 16; f++) {
            float4 wv = w4[f];
            float4 x0 = e4_0[f];
            float4 x1 = e4_1[f];
            float4 x2 = e4_2[f];
            float4 x3 = e4_3[f];
            a0 = fmaf(x0.x, wv.x, a0); a0 = fmaf(x0.y, wv.y, a0);
            a0 = fmaf(x0.z, wv.z, a0); a0 = fmaf(x0.w, wv.w, a0);
            a1 = fmaf(x1.x, wv.x, a1); a1 = fmaf(x1.y, wv.y, a1);
            a1 = fmaf(x1.z, wv.z, a1); a1 = fmaf(x1.w, wv.w, a1);
            a2 = fmaf(x2.x, wv.x, a2); a2 = fmaf(x2.y, wv.y, a2);
            a2 = fmaf(x2.z, wv.z, a2); a2 = fmaf(x2.w, wv.w, a2);
            a3 = fmaf(x3.x, wv.x, a3); a3 = fmaf(x3.y, wv.y, a3);
            a3 = fmaf(x3.z, wv.z, a3); a3 = fmaf(x3.w, wv.w, a3);
        }
        zxs[wave * 8 + 0 + half][l] = a0;
        zxs[wave * 8 + 2 + half][l] = a1;
        zxs[wave * 8 + 4 + half][l] = a2;
        zxs[wave * 8 + 6 + half][l] = a3;
    }
    __syncthreads();

    // ---- Phase 2: serial LSTM scan (lanes 0..31 of wave 0), DPP (r7) ----
    if (t < 32) {
        const int g = t >> 3;
        const int h = t & 7;
        const int q = t & 7;
        float wh[8], wo[8];
        #pragma unroll
        for (int k = 0; k < 8; k++) wh[k] = Win[t * FAN_ + 64 + k];
        #pragma unroll
        for (int k = 0; k < 8; k++) wo[k] = Wout[(g * 8 + h) * 8 + k];
        const float bo = b_out[g * 8 + h];

        float hxv[8];
        #pragma unroll
        for (int k = 0; k < 8; k++) hxv[k] = 0.f;
        float cx = 0.f;

        for (int s = 0; s < S_; s++) {
            float z = zxs[s][t];
            #pragma unroll
            for (int k = 0; k < 8; k++) z = fmaf(wh[k], hxv[k], z);

            float qc = __cosf(z);
            float u1 = dppf<0x111>(qc); qc = (q >= 1) ? qc * u1 : qc;
            float u2 = dppf<0x112>(qc); qc = (q >= 2) ? qc * u2 : qc;
            float u4 = dppf<0x114>(qc); qc = (q >= 4) ? qc * u4 : qc;

            float qch[8];
            bcast8(qc, t, qch);
            float pre = bo;
            #pragma unroll
            for (int qq = 0; qq < 8; qq++) pre = fmaf(wo[qq], qch[qq], pre);

            float e1 = lane_xor<8>(pre, t);
            float e2 = __shfl_xor(pre, 16, 64);
            float e3 = __shfl_xor(e1, 16, 64);
            float p0 = (g==0)?pre:(g==1)?e1:(g==2)?e2:e3;
            float p1 = (g==1)?pre:(g==0)?e1:(g==3)?e2:e3;
            float p2 = (g==2)?pre:(g==3)?e1:(g==0)?e2:e3;
            float p3 = (g==3)?pre:(g==2)?e1:(g==1)?e2:e3;

            float f_ = sigmoid_f(p0);
            float i_ = sigmoid_f(p1);
            float g_ = tanh_f(p2);
            float o_ = sigmoid_f(p3);
            cx = f_ * cx + i_ * g_;
            float hnew = o_ * tanh_f(cx);

            if (t < 8) sang[s][t] = hnew;
            bcast8(hnew, t, hxv);
        }
    }
    __syncthreads();

    // ---- Phase 3: constexpr QFC + measure + head + log_softmax ----
    // precompute RX(phiq) cos/sin once (row-independent)
    float cq0 = __cosf(phiq[0]*0.5f), sq0 = __sinf(phiq[0]*0.5f);
    float cq1 = __cosf(phiq[1]*0.5f), sq1 = __sinf(phiq[1]*0.5f);
    float cq2 = __cosf(phiq[2]*0.5f), sq2 = __sinf(phiq[2]*0.5f);
    float cq3 = __cosf(phiq[3]*0.5f), sq3 = __sinf(phiq[3]*0.5f);
    float cq4 = __cosf(phiq[4]*0.5f), sq4 = __sinf(phiq[4]*0.5f);
    float cq5 = __cosf(phiq[5]*0.5f), sq5 = __sinf(phiq[5]*0.5f);
    float cq6 = __cosf(phiq[6]*0.5f), sq6 = __sinf(phiq[6]*0.5f);
    float cq7 = __cosf(phiq[7]*0.5f), sq7 = __sinf(phiq[7]*0.5f);

    for (int r = 0; r < 4; r++) {
        const int s = half3 * 64 + wave * 4 + r;

        float ar[4], ai[4];
        {
            V2 v0 = init_wire<0>(sang[s][0] * 0.5f);
            V2 v1 = init_wire<1>(sang[s][1] * 0.5f);
            V2 v2 = init_wire<2>(sang[s][2] * 0.5f);
            V2 v3 = init_wire<3>(sang[s][3] * 0.5f);
            V2 v4 = init_wire<4>(sang[s][4] * 0.5f);
            V2 v5 = init_wire<5>(sang[s][5] * 0.5f);
            V2 v6 = init_wire<6>(sang[s][6] * 0.5f);
            V2 v7 = init_wire<7>(sang[s][7] * 0.5f);
            float Pr = 1.f, Pi = 0.f;
            {
                int bit = (lane >> 5) & 1;
                float er = bit ? v0.r1 : v0.r0, ei = bit ? v0.i1 : v0.i0;
                float nr = Pr*er - Pi*ei, ni = Pr*ei + Pi*er; Pr = nr; Pi = ni;
            }
            {
                int bit = (lane >> 4) & 1;
                float er = bit ? v1.r1 : v1.r0, ei = bit ? v1.i1 : v1.i0;
                float nr = Pr*er - Pi*ei, ni = Pr*ei + Pi*er; Pr = nr; Pi = ni;
            }
            {
                int bit = (lane >> 3) & 1;
                float er = bit ? v2.r1 : v2.r0, ei = bit ? v2.i1 : v2.i0;
                float nr = Pr*er - Pi*ei, ni = Pr*ei + Pi*er; Pr = nr; Pi = ni;
            }
            {
                int bit = (lane >> 2) & 1;
                float er = bit ? v3.r1 : v3.r0, ei = bit ? v3.i1 : v3.i0;
                float nr = Pr*er - Pi*ei, ni = Pr*ei + Pi*er; Pr = nr; Pi = ni;
            }
            {
                int bit = (lane >> 1) & 1;
                float er = bit ? v4.r1 : v4.r0, ei = bit ? v4.i1 : v4.i0;
                float nr = Pr*er - Pi*ei, ni = Pr*ei + Pi*er; Pr = nr; Pi = ni;
            }
            {
                int bit = lane & 1;
                float er = bit ? v5.r1 : v5.r0, ei = bit ? v5.i1 : v5.i0;
                float nr = Pr*er - Pi*ei, ni = Pr*ei + Pi*er; Pr = nr; Pi = ni;
            }
            float t0r = Pr*v6.r0 - Pi*v6.i0, t0i = Pr*v6.i0 + Pi*v6.r0;
            float t1r = Pr*v6.r1 - Pi*v6.i1, t1i = Pr*v6.i1 + Pi*v6.r1;
            ar[0] = t0r*v7.r0 - t0i*v7.i0;  ai[0] = t0r*v7.i0 + t0i*v7.r0;
            ar[1] = t0r*v7.r1 - t0i*v7.i1;  ai[1] = t0r*v7.i1 + t0i*v7.r1;
            ar[2] = t1r*v7.r0 - t1i*v7.i0;  ai[2] = t1r*v7.i0 + t1i*v7.r0;
            ar[3] = t1r*v7.r1 - t1i*v7.i1;  ai[3] = t1r*v7.i1 + t1i*v7.r1;
        }

        // middle ops — fully unrolled, literal coefficients
        run_ops<0>(lane, ar, ai);

        // trailing per-wire: F_w = RX(phiq_w) * endM_w
        final_wire<0>(cq0, sq0, lane, ar, ai);
        final_wire<1>(cq1, sq1, lane, ar, ai);
        final_wire<2>(cq2, sq2, lane, ar, ai);
        final_wire<3>(cq3, sq3, lane, ar, ai);
        final_wire<4>(cq4, sq4, lane, ar, ai);
        final_wire<5>(cq5, sq5, lane, ar, ai);
        final_wire<6>(cq6, sq6, lane, ar, ai);
        final_wire<7>(cq7, sq7, lane, ar, ai);

        // measure <Z_w>: Walsh-Hadamard on pt for lane wires; sums for 6,7
        float p0 = ar[0]*ar[0] + ai[0]*ai[0];
        float p1 = ar[1]*ar[1] + ai[1]*ai[1];
        float p2 = ar[2]*ar[2] + ai[2]*ai[2];
        float p3 = ar[3]*ar[3] + ai[3]*ai[3];
        float pt = p0 + p1 + p2 + p3;
        float a6 = p0 + p1 - p2 - p3;
        float a7 = p0 - p1 + p2 - p3;
        {
            float tv;
            tv = lane_xor<1>(pt, lane);  pt = (lane & 1)  ? (tv - pt) : (tv + pt);
            tv = lane_xor<2>(pt, lane);  pt = (lane & 2)  ? (tv - pt) : (tv + pt);
            tv = lane_xor<4>(pt, lane);  pt = (lane & 4)  ? (tv - pt) : (tv + pt);
            tv = lane_xor<8>(pt, lane);  pt = (lane & 8)  ? (tv - pt) : (tv + pt);
            tv = lane_xor<16>(pt, lane); pt = (lane & 16) ? (tv - pt) : (tv + pt);
            tv = lane_xor<32>(pt, lane); pt = (lane & 32) ? (tv - pt) : (tv + pt);
            a6 += lane_xor<1>(a6, lane);  a6 += lane_xor<2>(a6, lane);
            a6 += lane_xor<4>(a6, lane);  a6 += lane_xor<8>(a6, lane);
            a6 += lane_xor<16>(a6, lane); a6 += lane_xor<32>(a6, lane);
            a7 += lane_xor<1>(a7, lane);  a7 += lane_xor<2>(a7, lane);
            a7 += lane_xor<4>(a7, lane);  a7 += lane_xor<8>(a7, lane);
            a7 += lane_xor<16>(a7, lane); a7 += lane_xor<32>(a7, lane);
        }
        float zl[8];
        zl[0] = __shfl(pt, 32, 64);
        zl[1] = __shfl(pt, 16, 64);
        zl[2] = __shfl(pt, 8, 64);
        zl[3] = __shfl(pt, 4, 64);
        zl[4] = __shfl(pt, 2, 64);
        zl[5] = __shfl(pt, 1, 64);
        zl[6] = a6;
        zl[7] = a7;

        float logit = -1e30f;
        if (lane < T_) {
            logit = b_head[lane];
            #pragma unroll
            for (int w = 0; w < 8; w++)
                logit = fmaf(zl[w], Whead[lane * 8 + w], logit);
        }
        float mx = logit;
        mx = fmaxf(mx, lane_xor<1>(mx, lane));
        mx = fmaxf(mx, lane_xor<2>(mx, lane));
        mx = fmaxf(mx, lane_xor<4>(mx, lane));
        mx = fmaxf(mx, lane_xor<8>(mx, lane));
        float e = (lane < T_) ? __expf(logit - mx) : 0.f;
        float se = e;
        se += lane_xor<1>(se, lane);
        se += lane_xor<2>(se, lane);
        se += lane_xor<4>(se, lane);
        se += lane_xor<8>(se, lane);
        if (lane < T_)
            out[(b * S_ + s) * T_ + lane] = logit - mx - __logf(se);
    }
}

// ---------------------------------------------------------------------------
extern "C" void kernel_launch(void* const* d_in, const int* in_sizes, int n_in,
                              void* d_out, int out_size, void* d_ws, size_t ws_size,
                              hipStream_t stream)
{
    (void)in_sizes; (void)n_in; (void)out_size; (void)d_ws; (void)ws_size;
    const float* emb    = (const float*)d_in[0];
    const float* Win    = (const float*)d_in[1];
    const float* b_in   = (const float*)d_in[2];
    const float* phi    = (const float*)d_in[3];
    const float* Wout   = (const float*)d_in[4];
    const float* b_out  = (const float*)d_in[5];
    const float* phiq   = (const float*)d_in[6];
    const float* Whead  = (const float*)d_in[7];
    const float* b_head = (const float*)d_in[8];
    const int* sentence = (const int*)d_in[9];
    float* out          = (float*)d_out;

    hipLaunchKernelGGL(k_fused, dim3(2 * B_), dim3(1024), 0, stream,
                       emb, sentence, Win, b_in, phi, Wout, b_out,
                       phiq, Whead, b_head, out);
}